// Round 11
// baseline (2001.407 us; speedup 1.0000x reference)
//
#include <hip/hip_runtime.h>

#define DEV __device__ __forceinline__

typedef __attribute__((ext_vector_type(8))) short short8;
typedef __attribute__((ext_vector_type(8))) __bf16 bf16x8;
typedef __attribute__((ext_vector_type(4))) float f32x4;

// ---------- constants ----------
// N=32, T=1024, D=1152, H=16, DH=72, MLP=4608
#define TD      1024
#define DD      1152
#define DHH     72
#define MLPD    4608
#define QKVN    3456
#define ADAN    6912
#define MROWS   32768

DEV unsigned short f32_to_bf16(float f) {
  unsigned int u = __float_as_uint(f);
  u += 0x7fffu + ((u >> 16) & 1u);
  return (unsigned short)(u >> 16);
}

DEV void gl16(const void* g, void* l) {
  __builtin_amdgcn_global_load_lds((__attribute__((address_space(1))) void*)g,
                                   (__attribute__((address_space(3))) void*)l,
                                   16, 0, 0);
}

DEV bf16x8 zero_bf16x8() {
  short8 z = {0, 0, 0, 0, 0, 0, 0, 0};
  return __builtin_bit_cast(bf16x8, z);
}

DEV float gelu_exact(float v) {
  return 0.5f * v * (1.0f + erff(v * 0.70710678118654752f));
}

#define WAITV(n) asm volatile("s_waitcnt vmcnt(" #n ")" ::: "memory")

// ---------------- weight transform: fp32 W[K][N] -> bf16 B' in MFMA-frag order ----------
// B' chunk layout: for n16 = n>>4, kb = k>>5: 1KB chunk at n16*(K*16) + kb*512 (shorts).
// Within chunk, element for (n,k): ((n&15) + ((k>>3)&3)*16)*8 + (k&7)  — i.e. lane l of a
// wave reading [lane*8 .. lane*8+7] gets exactly its 16x16x32 B-fragment (col=l&15,
// k = kb*32 + (l>>4)*8 + j). One global_load_dwordx4 per frag, fully coalesced.
__global__ __launch_bounds__(256) void wtrans_frag(const float* __restrict__ W,
                                                   unsigned short* __restrict__ Bp,
                                                   int K, int N) {
  const int nb = blockIdx.x * 32, kb = blockIdx.y * 32;
  const int tx = threadIdx.x, ty = threadIdx.y;  // block (32,8)
  const size_t K16 = (size_t)K << 4;
  #pragma unroll
  for (int i = 0; i < 4; ++i) {
    const int k = kb + ty + i * 8;
    const int n = nb + tx;
    const unsigned short v = f32_to_bf16(W[(size_t)k * N + n]);
    Bp[(size_t)(n >> 4) * K16 + (size_t)(k >> 5) * 512 +
       (size_t)(((n & 15) + ((k >> 3) & 3) * 16) * 8 + (k & 7))] = v;
  }
}

// ---------------- ada = silu(c) @ ada_w + ada_b  (fp32) ----------------
__global__ __launch_bounds__(256) void ada_kernel(const float* __restrict__ c,
                                                  const float* __restrict__ ada_w,
                                                  const float* __restrict__ ada_b,
                                                  float* __restrict__ ada_out) {
  __shared__ float sc[DD];
  const int n = blockIdx.y;
  const int col = blockIdx.x * 256 + threadIdx.x;
  for (int i = threadIdx.x; i < DD; i += 256) {
    float v = c[(size_t)n * DD + i];
    sc[i] = v / (1.0f + __expf(-v));
  }
  __syncthreads();
  float acc = ada_b[col];
  #pragma unroll 8
  for (int k = 0; k < DD; ++k)
    acc += sc[k] * ada_w[(size_t)k * ADAN + col];
  ada_out[(size_t)n * ADAN + col] = acc;
}

// ---------------- LayerNorm + modulate -> bf16 ----------------
__global__ __launch_bounds__(256) void ln_mod_kernel(const float* __restrict__ X,
                                                     const float* __restrict__ ada,
                                                     int soff,
                                                     unsigned short* __restrict__ out) {
  const int row = blockIdx.x;
  const int batch = row >> 10;
  const float* xr = X + (size_t)row * DD;
  const int t = threadIdx.x;

  float4 v0 = reinterpret_cast<const float4*>(xr)[t];
  float4 v1 = make_float4(0.f, 0.f, 0.f, 0.f);
  const bool has2 = (t < 32);
  if (has2) v1 = reinterpret_cast<const float4*>(xr)[256 + t];

  float s  = v0.x + v0.y + v0.z + v0.w + v1.x + v1.y + v1.z + v1.w;
  float sq = v0.x*v0.x + v0.y*v0.y + v0.z*v0.z + v0.w*v0.w
           + v1.x*v1.x + v1.y*v1.y + v1.z*v1.z + v1.w*v1.w;
  #pragma unroll
  for (int m = 1; m < 64; m <<= 1) {
    s  += __shfl_xor(s, m);
    sq += __shfl_xor(sq, m);
  }
  __shared__ float red[8];
  const int wv = t >> 6;
  if ((t & 63) == 0) { red[wv] = s; red[4 + wv] = sq; }
  __syncthreads();
  s  = red[0] + red[1] + red[2] + red[3];
  sq = red[4] + red[5] + red[6] + red[7];
  const float mean = s * (1.0f / 1152.0f);
  const float var  = sq * (1.0f / 1152.0f) - mean * mean;
  const float rstd = rsqrtf(var + 1e-6f);

  const float* shp = ada + (size_t)batch * ADAN + soff;
  const float* scp = shp + DD;
  unsigned short* orow = out + (size_t)row * DD;

  {
    const int col = t * 4;
    ushort4 o4;
    o4.x = f32_to_bf16((v0.x - mean) * rstd * (1.0f + scp[col + 0]) + shp[col + 0]);
    o4.y = f32_to_bf16((v0.y - mean) * rstd * (1.0f + scp[col + 1]) + shp[col + 1]);
    o4.z = f32_to_bf16((v0.z - mean) * rstd * (1.0f + scp[col + 2]) + shp[col + 2]);
    o4.w = f32_to_bf16((v0.w - mean) * rstd * (1.0f + scp[col + 3]) + shp[col + 3]);
    reinterpret_cast<ushort4*>(orow)[t] = o4;
  }
  if (has2) {
    const int col = 1024 + t * 4;
    ushort4 o4;
    o4.x = f32_to_bf16((v1.x - mean) * rstd * (1.0f + scp[col + 0]) + shp[col + 0]);
    o4.y = f32_to_bf16((v1.y - mean) * rstd * (1.0f + scp[col + 1]) + shp[col + 1]);
    o4.z = f32_to_bf16((v1.z - mean) * rstd * (1.0f + scp[col + 2]) + shp[col + 2]);
    o4.w = f32_to_bf16((v1.w - mean) * rstd * (1.0f + scp[col + 3]) + shp[col + 3]);
    reinterpret_cast<ushort4*>(orow)[256 + t] = o4;
  }
}

// ---------------- GEMM (A via LDS, B via direct frag loads): C = A * B + epilogue ----------
// BM=BN=256, BK=64, 8 waves (wm 0-1, wn 0-3). Wave sub-tiles INTERLEAVED (as R7):
//   rows = wm*64 + mq*128 + mf*16 + (lg*4+r);  cols = wn*32 + nq*128 + nf*16 + l15
// A: gl16-staged, ring-2 LDS 64KB total (chunk-XOR layout, conflict-free, coalesced).
// B: loaded per-wave straight from frag-ordered B' (global, L2/L3-hot) — no LDS at all.
// Per K-tile: issue {4 gl16 A(t+1), 8 dwordx4 B(t+1)} -> 4 sub-phases of
// {4 ds_read_b128 A-frags + 16 MFMA} -> WAITV(0) (everything ~full tile old) -> 1 barrier.
// The single barrier also guards staging WAR (ring-2: stage target was read at tile t-1).
// B registers double-buffered via unroll-by-2 with static names (no runtime indexing).
// EPI: 0 = +bias->bf16; 1 = resid+gate*(+bias)->f32; 2 = gelu(+bias)->bf16; 3 = +=gate*(+bias)
template <int EPI>
__global__ __launch_bounds__(512) void gemmB(
    const unsigned short* __restrict__ A, const unsigned short* __restrict__ Bp,
    const float* __restrict__ bias, const float* __restrict__ ada, int ada_off,
    const float* __restrict__ resid, unsigned short* __restrict__ out_bf,
    float* __restrict__ out_f, int N, int K, int ntn) {
  __shared__ unsigned short lds[32768];  // 2 bufs x A 256x64 bf16 = 64KB
  const int tid = threadIdx.x;
  const int lane = tid & 63, w = tid >> 6;
  const int wm = w >> 2, wn = w & 3;
  const int l15 = lane & 15, lg = lane >> 4;

  // T1 XCD swizzle (nwg = 128*ntn, always %8==0)
  const int nwg = 128 * ntn, cpx = nwg >> 3;
  const int wg = (blockIdx.x & 7) * cpx + (blockIdx.x >> 3);
  const int bm = wg / ntn, bn = wg - bm * ntn;

  const unsigned short* __restrict__ Ag = A + (size_t)bm * 256 * K;
  const size_t K16 = (size_t)K << 4;
  // wave's B base: n16 = bn*16 + wn*2, + per-lane 16B
  const unsigned short* __restrict__ Bgl = Bp + (size_t)(bn * 16 + wn * 2) * K16 + lane * 8;

  // A staging: round r covers rows r*64 + (tid>>3); storage chunk tid&7 holds logical
  // chunk (tid&7)^(row&7) -> pre-permuted global source, linear LDS dest.
  const int rp0 = tid >> 3;
  const int ch0 = ((tid & 7) ^ (rp0 & 7)) * 8;

#define STG_A(BUFS, KT) do {                                                              \
    gl16(Ag + (size_t)(rp0) * K + (size_t)(KT) * 64 + ch0, &lds[(BUFS) + tid * 8]);       \
    gl16(Ag + (size_t)(rp0 + 64) * K + (size_t)(KT) * 64 + ch0,                           \
         &lds[(BUFS) + 4096 + tid * 8]);                                                  \
    gl16(Ag + (size_t)(rp0 + 128) * K + (size_t)(KT) * 64 + ch0,                          \
         &lds[(BUFS) + 8192 + tid * 8]);                                                  \
    gl16(Ag + (size_t)(rp0 + 192) * K + (size_t)(KT) * 64 + ch0,                          \
         &lds[(BUFS) + 12288 + tid * 8]);                                                 \
  } while (0)

#define LOAD_B(DST, KT) do {                                                              \
    _Pragma("unroll") for (int nq_ = 0; nq_ < 2; ++nq_)                                   \
      _Pragma("unroll") for (int nf_ = 0; nf_ < 2; ++nf_)                                 \
        _Pragma("unroll") for (int kb_ = 0; kb_ < 2; ++kb_)                               \
          DST[nq_][nf_][kb_] = *(const bf16x8*)&Bgl[(size_t)(nq_ * 8 + nf_) * K16 +       \
                                                    ((KT) * 2 + kb_) * 512];              \
  } while (0)

  // A frag read chunk offsets (shorts): kb0: (lg^(l15&7))*8, kb1: ^32
  const int chA0 = (lg ^ (l15 & 7)) * 8;
  const int chA1 = chA0 ^ 32;
  const int arow0 = wm * 64 + l15;  // + mq*128 + mf*16; row stride 64 shorts

  f32x4 acc[2][2][4][2];
  #pragma unroll
  for (int a = 0; a < 2; ++a)
    #pragma unroll
    for (int b = 0; b < 2; ++b)
      #pragma unroll
      for (int m = 0; m < 4; ++m)
        #pragma unroll
        for (int n2 = 0; n2 < 2; ++n2)
          acc[a][b][m][n2] = (f32x4){0.f, 0.f, 0.f, 0.f};

#define SUBPH(MQ, KB, BSET) do {                                                          \
    bf16x8 af_[4];                                                                        \
    _Pragma("unroll") for (int mf_ = 0; mf_ < 4; ++mf_)                                   \
      af_[mf_] = *(const bf16x8*)&lb[(arow0 + (MQ) * 128 + mf_ * 16) * 64 +               \
                                     ((KB) ? chA1 : chA0)];                               \
    __builtin_amdgcn_s_setprio(1);                                                        \
    _Pragma("unroll") for (int mf_ = 0; mf_ < 4; ++mf_)                                   \
      _Pragma("unroll") for (int nq_ = 0; nq_ < 2; ++nq_)                                 \
        _Pragma("unroll") for (int nf_ = 0; nf_ < 2; ++nf_)                               \
          acc[MQ][nq_][mf_][nf_] = __builtin_amdgcn_mfma_f32_16x16x32_bf16(               \
              af_[mf_], BSET[nq_][nf_][KB], acc[MQ][nq_][mf_][nf_], 0, 0, 0);             \
    __builtin_amdgcn_s_setprio(0);                                                        \
  } while (0)

#define TILE(T, BCUR, BNXT) do {                                                          \
    const unsigned short* lb = lds + (((T) & 1) << 14);                                   \
    STG_A((((T) + 1) & 1) << 14, (T) + 1);                                                \
    LOAD_B(BNXT, (T) + 1);                                                                \
    SUBPH(0, 0, BCUR);                                                                    \
    SUBPH(0, 1, BCUR);                                                                    \
    SUBPH(1, 0, BCUR);                                                                    \
    SUBPH(1, 1, BCUR);                                                                    \
    WAITV(0);                                                                             \
    __builtin_amdgcn_s_barrier();                                                         \
  } while (0)

  const int NT = K >> 6;  // 18 or 72 — always even

  bf16x8 BX[2][2][2], BY[2][2][2];

  // prologue: tile 0 fully staged/loaded, then barrier
  STG_A(0, 0);
  LOAD_B(BX, 0);
  WAITV(0);
  __builtin_amdgcn_s_barrier();

  for (int t = 0; t < NT - 2; t += 2) {
    TILE(t, BX, BY);
    TILE(t + 1, BY, BX);
  }
  TILE(NT - 2, BX, BY);
  {  // tail tile NT-1: no staging, data validated by TILE(NT-2)'s WAITV+bar
    const unsigned short* lb = lds + (((NT - 1) & 1) << 14);
    SUBPH(0, 0, BY);
    SUBPH(0, 1, BY);
    SUBPH(1, 0, BY);
    SUBPH(1, 1, BY);
  }
#undef STG_A
#undef LOAD_B
#undef SUBPH
#undef TILE

  // epilogue (identical indexing to R7)
  const int batch = bm >> 2;
  #pragma unroll
  for (int nq = 0; nq < 2; ++nq) {
    const int colbase = bn * 256 + nq * 128 + wn * 32;
    if (colbase >= N) continue;  // masked pad tile (wave-uniform)
    #pragma unroll
    for (int nf = 0; nf < 2; ++nf) {
      const int colg = colbase + nf * 16 + l15;
      const float bv = bias[colg];
      float g2 = 0.0f;
      if constexpr (EPI == 1 || EPI == 3) g2 = ada[(size_t)batch * ADAN + ada_off + colg];
      #pragma unroll
      for (int mq = 0; mq < 2; ++mq) {
        #pragma unroll
        for (int mf = 0; mf < 4; ++mf) {
          #pragma unroll
          for (int r = 0; r < 4; ++r) {
            const size_t row = (size_t)bm * 256 + wm * 64 + mq * 128 + mf * 16 + lg * 4 + r;
            const size_t idx = row * (size_t)N + colg;
            const float v = acc[mq][nq][mf][nf][r] + bv;
            if constexpr (EPI == 0)      out_bf[idx] = f32_to_bf16(v);
            else if constexpr (EPI == 2) out_bf[idx] = f32_to_bf16(gelu_exact(v));
            else if constexpr (EPI == 1) out_f[idx] = resid[idx] + g2 * v;
            else                         out_f[idx] = out_f[idx] + g2 * v;
          }
        }
      }
    }
  }
}

// ---------------- per-token head attention ----------------
__global__ __launch_bounds__(256) void attn_kernel(const unsigned short* __restrict__ qkv,
                                                   unsigned short* __restrict__ y) {
  const int tid = threadIdx.x, w = tid >> 6, lane = tid & 63;
  const int l15 = lane & 15, lg = lane >> 4;
  const int tok = blockIdx.x * 4 + w;
  const int n = tok >> 10, t = tok & 1023;

  __shared__ unsigned short Pl[4][16 * 32];
  __shared__ unsigned short Vl[4][16 * 80];

  for (int i = lane; i < 16 * 32; i += 64)
    if ((i & 31) >= 16) Pl[w][i] = 0;

  const size_t rowb = (size_t)tok * QKVN;
  const float scale = 0.11785113019775793f;  // 72^-0.5

  bf16x8 aq[3];
  #pragma unroll
  for (int kk = 0; kk < 3; ++kk) {
    const int d0 = kk * 32 + lg * 8;
    aq[kk] = (d0 < DHH) ? *(const bf16x8*)&qkv[rowb + l15 * DHH + d0] : zero_bf16x8();
  }

  for (int c = lane; c < 144; c += 64) {
    const int r = c / 9, cc = (c % 9) * 8;
    *(short8*)&Vl[w][r * 80 + cc] = *(const short8*)&qkv[rowb + 2 * DD + r * DHH + cc];
  }

  f32x4 s = (f32x4){0.f, 0.f, 0.f, 0.f};
  #pragma unroll
  for (int kk = 0; kk < 3; ++kk) {
    const int d0 = kk * 32 + lg * 8;
    bf16x8 bk = (d0 < DHH) ? *(const bf16x8*)&qkv[rowb + DD + l15 * DHH + d0] : zero_bf16x8();
    s = __builtin_amdgcn_mfma_f32_16x16x32_bf16(aq[kk], bk, s, 0, 0, 0);
  }

  float p[4], mx[4], ssum[4];
  #pragma unroll
  for (int r = 0; r < 4; ++r) { p[r] = s[r] * scale; mx[r] = p[r]; }
  #pragma unroll
  for (int mk = 1; mk <= 8; mk <<= 1)
    #pragma unroll
    for (int r = 0; r < 4; ++r) mx[r] = fmaxf(mx[r], __shfl_xor(mx[r], mk));
  #pragma unroll
  for (int r = 0; r < 4; ++r) { p[r] = __expf(p[r] - mx[r]); ssum[r] = p[r]; }
  #pragma unroll
  for (int mk = 1; mk <= 8; mk <<= 1)
    #pragma unroll
    for (int r = 0; r < 4; ++r) ssum[r] += __shfl_xor(ssum[r], mk);

  #pragma unroll
  for (int r = 0; r < 4; ++r)
    Pl[w][(lg * 4 + r) * 32 + l15] = f32_to_bf16(p[r] / ssum[r]);

  bf16x8 pa = *(const bf16x8*)&Pl[w][l15 * 32 + lg * 8];
  const int kb = (lg & 1) * 8;
  f32x4 o[5];
  #pragma unroll
  for (int df = 0; df < 5; ++df) {
    short8 bvv;
    #pragma unroll
    for (int j = 0; j < 8; ++j)
      bvv[j] = (short)Vl[w][(kb + j) * 80 + df * 16 + l15];
    o[df] = __builtin_amdgcn_mfma_f32_16x16x32_bf16(
        pa, __builtin_bit_cast(bf16x8, bvv), (f32x4){0.f, 0.f, 0.f, 0.f}, 0, 0, 0);
  }

  unsigned short* yb = y + (size_t)n * (TD * DD);
  #pragma unroll
  for (int df = 0; df < 5; ++df) {
    const int d = df * 16 + l15;
    if (d < DHH) {
      #pragma unroll
      for (int r = 0; r < 4; ++r) {
        const int h = lg * 4 + r;
        yb[h * 73728 + t * DHH + d] = f32_to_bf16(o[df][r]);
      }
    }
  }
}

// ---------------- host launch ----------------
extern "C" void kernel_launch(void* const* d_in, const int* in_sizes, int n_in,
                              void* d_out, int out_size, void* d_ws, size_t ws_size,
                              hipStream_t stream) {
  (void)in_sizes; (void)n_in; (void)out_size; (void)ws_size;
  const float* x      = (const float*)d_in[0];
  const float* c      = (const float*)d_in[1];
  const float* qkv_w  = (const float*)d_in[2];
  const float* qkv_b  = (const float*)d_in[3];
  const float* proj_w = (const float*)d_in[4];
  const float* proj_b = (const float*)d_in[5];
  const float* fc1_w  = (const float*)d_in[6];
  const float* fc1_b  = (const float*)d_in[7];
  const float* fc2_w  = (const float*)d_in[8];
  const float* fc2_b  = (const float*)d_in[9];
  const float* ada_w  = (const float*)d_in[10];
  const float* ada_b  = (const float*)d_in[11];
  float* out = (float*)d_out;

  char* ws = (char*)d_ws;
  unsigned short* hbuf    = (unsigned short*)ws;               // 302MB region (qkv | attn-y | h)
  unsigned short* qkvbuf  = hbuf;
  unsigned short* attnbuf = hbuf + (size_t)MROWS * QKVN;
  size_t off = 301989888ull;
  unsigned short* xm    = (unsigned short*)(ws + off); off += 75497472ull;
  // frag-ordered B' buffers, cols padded to x256 (pad region read-as-garbage, masked)
  unsigned short* wtq   = (unsigned short*)(ws + off); off += (size_t)3584 * DD * 2;
  unsigned short* wtp   = (unsigned short*)(ws + off); off += (size_t)1280 * DD * 2;
  unsigned short* wtf1  = (unsigned short*)(ws + off); off += (size_t)4608 * DD * 2;
  unsigned short* wtf2  = (unsigned short*)(ws + off); off += (size_t)1280 * MLPD * 2;
  float*          adab  = (float*)(ws + off); off += 884736ull;

  const dim3 tb(32, 8);
  hipLaunchKernelGGL(wtrans_frag, dim3(QKVN / 32, DD / 32), tb, 0, stream, qkv_w, wtq, DD, QKVN);
  hipLaunchKernelGGL(wtrans_frag, dim3(DD / 32, DD / 32),   tb, 0, stream, proj_w, wtp, DD, DD);
  hipLaunchKernelGGL(wtrans_frag, dim3(MLPD / 32, DD / 32), tb, 0, stream, fc1_w, wtf1, DD, MLPD);
  hipLaunchKernelGGL(wtrans_frag, dim3(DD / 32, MLPD / 32), tb, 0, stream, fc2_w, wtf2, MLPD, DD);

  hipLaunchKernelGGL(ada_kernel, dim3(ADAN / 256, 32), dim3(256), 0, stream, c, ada_w, ada_b, adab);

  hipLaunchKernelGGL(ln_mod_kernel, dim3(MROWS), dim3(256), 0, stream, x, adab, 0, xm);

  // qkv: N=3456 -> 14 n-tiles (last masked to 128 cols)
  hipLaunchKernelGGL((gemmB<0>), dim3(128 * 14), dim3(512), 0, stream,
                     xm, wtq, qkv_b, nullptr, 0, nullptr, qkvbuf, nullptr, QKVN, DD, 14);

  hipLaunchKernelGGL(attn_kernel, dim3(MROWS / 4), dim3(256), 0, stream, qkvbuf, attnbuf);

  // proj: N=1152 -> 5 n-tiles (last masked)
  hipLaunchKernelGGL((gemmB<1>), dim3(128 * 5), dim3(512), 0, stream,
                     attnbuf, wtp, proj_b, adab, 2304, x, nullptr, out, DD, DD, 5);

  hipLaunchKernelGGL(ln_mod_kernel, dim3(MROWS), dim3(256), 0, stream, out, adab, 3456, xm);

  // fc1: N=4608 -> 18 exact
  hipLaunchKernelGGL((gemmB<2>), dim3(128 * 18), dim3(512), 0, stream,
                     xm, wtf1, fc1_b, nullptr, 0, nullptr, hbuf, nullptr, MLPD, DD, 18);

  // fc2: N=1152 -> 5 (last masked), K=4608
  hipLaunchKernelGGL((gemmB<3>), dim3(128 * 5), dim3(512), 0, stream,
                     hbuf, wtf2, fc2_b, adab, 5760, nullptr, nullptr, out, DD, MLPD, 5);
}

// Round 13
// 1755.177 us; speedup vs baseline: 1.1403x; 1.1403x over previous
//
#include <hip/hip_runtime.h>

#define DEV __device__ __forceinline__

typedef __attribute__((ext_vector_type(8))) short short8;
typedef __attribute__((ext_vector_type(8))) __bf16 bf16x8;
typedef __attribute__((ext_vector_type(4))) float f32x4;

// ---------- constants ----------
// N=32, T=1024, D=1152, H=16, DH=72, MLP=4608
#define TD      1024
#define DD      1152
#define DHH     72
#define MLPD    4608
#define QKVN    3456
#define ADAN    6912
#define MROWS   32768

DEV unsigned short f32_to_bf16(float f) {
  unsigned int u = __float_as_uint(f);
  u += 0x7fffu + ((u >> 16) & 1u);
  return (unsigned short)(u >> 16);
}

DEV void gl16(const void* g, void* l) {
  __builtin_amdgcn_global_load_lds((__attribute__((address_space(1))) void*)g,
                                   (__attribute__((address_space(3))) void*)l,
                                   16, 0, 0);
}

DEV bf16x8 zero_bf16x8() {
  short8 z = {0, 0, 0, 0, 0, 0, 0, 0};
  return __builtin_bit_cast(bf16x8, z);
}

DEV float gelu_exact(float v) {
  return 0.5f * v * (1.0f + erff(v * 0.70710678118654752f));
}

#define WAITV(n) asm volatile("s_waitcnt vmcnt(" #n ")" ::: "memory")

// ---------------- weight transpose: fp32 W[K][N] -> bf16 Wt[N][K] ----------------
__global__ __launch_bounds__(256) void wtrans_kernel(const float* __restrict__ W,
                                                     unsigned short* __restrict__ Wt,
                                                     int K, int N) {
  __shared__ unsigned short tile[32][33];
  const int nb = blockIdx.x * 32, kb = blockIdx.y * 32;
  const int tx = threadIdx.x, ty = threadIdx.y;  // block (32,8)
  #pragma unroll
  for (int i = ty; i < 32; i += 8)
    tile[i][tx] = f32_to_bf16(W[(size_t)(kb + i) * N + nb + tx]);
  __syncthreads();
  #pragma unroll
  for (int i = ty; i < 32; i += 8)
    Wt[(size_t)(nb + i) * K + kb + tx] = tile[tx][i];
}

// ---------------- ada = silu(c) @ ada_w + ada_b  (fp32) ----------------
__global__ __launch_bounds__(256) void ada_kernel(const float* __restrict__ c,
                                                  const float* __restrict__ ada_w,
                                                  const float* __restrict__ ada_b,
                                                  float* __restrict__ ada_out) {
  __shared__ float sc[DD];
  const int n = blockIdx.y;
  const int col = blockIdx.x * 256 + threadIdx.x;
  for (int i = threadIdx.x; i < DD; i += 256) {
    float v = c[(size_t)n * DD + i];
    sc[i] = v / (1.0f + __expf(-v));
  }
  __syncthreads();
  float acc = ada_b[col];
  #pragma unroll 8
  for (int k = 0; k < DD; ++k)
    acc += sc[k] * ada_w[(size_t)k * ADAN + col];
  ada_out[(size_t)n * ADAN + col] = acc;
}

// ---------------- LayerNorm + modulate -> bf16 ----------------
__global__ __launch_bounds__(256) void ln_mod_kernel(const float* __restrict__ X,
                                                     const float* __restrict__ ada,
                                                     int soff,
                                                     unsigned short* __restrict__ out) {
  const int row = blockIdx.x;
  const int batch = row >> 10;
  const float* xr = X + (size_t)row * DD;
  const int t = threadIdx.x;

  float4 v0 = reinterpret_cast<const float4*>(xr)[t];
  float4 v1 = make_float4(0.f, 0.f, 0.f, 0.f);
  const bool has2 = (t < 32);
  if (has2) v1 = reinterpret_cast<const float4*>(xr)[256 + t];

  float s  = v0.x + v0.y + v0.z + v0.w + v1.x + v1.y + v1.z + v1.w;
  float sq = v0.x*v0.x + v0.y*v0.y + v0.z*v0.z + v0.w*v0.w
           + v1.x*v1.x + v1.y*v1.y + v1.z*v1.z + v1.w*v1.w;
  #pragma unroll
  for (int m = 1; m < 64; m <<= 1) {
    s  += __shfl_xor(s, m);
    sq += __shfl_xor(sq, m);
  }
  __shared__ float red[8];
  const int wv = t >> 6;
  if ((t & 63) == 0) { red[wv] = s; red[4 + wv] = sq; }
  __syncthreads();
  s  = red[0] + red[1] + red[2] + red[3];
  sq = red[4] + red[5] + red[6] + red[7];
  const float mean = s * (1.0f / 1152.0f);
  const float var  = sq * (1.0f / 1152.0f) - mean * mean;
  const float rstd = rsqrtf(var + 1e-6f);

  const float* shp = ada + (size_t)batch * ADAN + soff;
  const float* scp = shp + DD;
  unsigned short* orow = out + (size_t)row * DD;

  {
    const int col = t * 4;
    ushort4 o4;
    o4.x = f32_to_bf16((v0.x - mean) * rstd * (1.0f + scp[col + 0]) + shp[col + 0]);
    o4.y = f32_to_bf16((v0.y - mean) * rstd * (1.0f + scp[col + 1]) + shp[col + 1]);
    o4.z = f32_to_bf16((v0.z - mean) * rstd * (1.0f + scp[col + 2]) + shp[col + 2]);
    o4.w = f32_to_bf16((v0.w - mean) * rstd * (1.0f + scp[col + 3]) + shp[col + 3]);
    reinterpret_cast<ushort4*>(orow)[t] = o4;
  }
  if (has2) {
    const int col = 1024 + t * 4;
    ushort4 o4;
    o4.x = f32_to_bf16((v1.x - mean) * rstd * (1.0f + scp[col + 0]) + shp[col + 0]);
    o4.y = f32_to_bf16((v1.y - mean) * rstd * (1.0f + scp[col + 1]) + shp[col + 1]);
    o4.z = f32_to_bf16((v1.z - mean) * rstd * (1.0f + scp[col + 2]) + shp[col + 2]);
    o4.w = f32_to_bf16((v1.w - mean) * rstd * (1.0f + scp[col + 3]) + shp[col + 3]);
    reinterpret_cast<ushort4*>(orow)[256 + t] = o4;
  }
}

// ---------------- GEMM: C[M][N] = A[M][K](bf16) * Bt[N][K](bf16)^T + epilogue ----------------
// BM=256, BN=128, BK=32, 512 threads / 8 waves (w=tid>>6: wm=w>>1 in 0..3, wn=w&1),
// wave-tile 64x64. Ring-2 LDS = 48KB -> 3 blocks/CU = 24 waves/CU: cross-block TLP
// hides latency (R2/m114 mechanism) while 256-row A panels keep intensity.
// Per K-tile: [STG next (3 gl16/thread) ; WAITV(3)] bar [8 ds_read_b128 + 16 MFMA] bar.
// LDS chunk-XOR (R5-proven, 0 conflicts): storage chunk c holds logical c^((row>>1)&3);
// linear gl16 dest + pre-permuted global src (quad stays within one 64B row segment).
// R12 BUG FIXED: was launched with 256 threads -> rows 128-255 never computed.
// EPI: 0 = +bias->bf16; 1 = resid+gate*(+bias)->f32; 2 = gelu(+bias)->bf16; 3 = +=gate*(+bias)
template <int EPI>
__global__ __launch_bounds__(512) void gemm3b(
    const unsigned short* __restrict__ A, const unsigned short* __restrict__ Bt,
    const float* __restrict__ bias, const float* __restrict__ ada, int ada_off,
    const float* __restrict__ resid, unsigned short* __restrict__ out_bf,
    float* __restrict__ out_f, int N, int K, int ntn) {
  __shared__ unsigned short lds[24576];  // 2 slots x (A 256x32 = 8192 sh | B 128x32 = 4096 sh)
  const int tid = threadIdx.x;
  const int lane = tid & 63, w = tid >> 6;
  const int wm = w >> 1, wn = w & 1;     // wm 0..3, wn 0..1
  const int l15 = lane & 15, lg = lane >> 4;

  // T1 XCD swizzle (nwg = 128*ntn, always %8==0); bn fastest within XCD (A-panel L2-hot)
  const int nwg = 128 * ntn, cpx = nwg >> 3;
  const int wg = (blockIdx.x & 7) * cpx + (blockIdx.x >> 3);
  const int bm = wg / ntn, bn = wg - bm * ntn;

  const unsigned short* __restrict__ Ag = A + (size_t)bm * 256 * K;
  const unsigned short* __restrict__ Bg = Bt + (size_t)bn * 128 * K;

  // staging decode (512 threads, 3 chunks each):
  //   A round 0: row tid>>2 (0..127);  A round 1: row (tid>>2)+128;  B: row tid>>2.
  //   logical chunk = (tid&3) ^ ((row>>1)&3) = (tid&3) ^ ((tid>>3)&3)  [rounds: +128 ≡ 0 mod 4]
  const int srow = tid >> 2;                            // 0..127
  const int gch = ((tid & 3) ^ ((tid >> 3) & 3)) * 8;   // shorts offset within row

#define STG(SL, KT) do {                                                                 \
    gl16(Ag + (size_t)srow * K + (size_t)(KT) * 32 + gch, &lds[(SL) + tid * 8]);         \
    gl16(Ag + (size_t)(srow + 128) * K + (size_t)(KT) * 32 + gch,                        \
         &lds[(SL) + 4096 + tid * 8]);                                                   \
    gl16(Bg + (size_t)srow * K + (size_t)(KT) * 32 + gch,                                \
         &lds[(SL) + 8192 + tid * 8]);                                                   \
  } while (0)

  // frag read offsets (shorts): chunk = (lg ^ ((l15>>1)&3))*8  [invariant across mf/wm]
  const int chA = (lg ^ ((l15 >> 1) & 3)) * 8;
  const int arow0 = wm * 64 + l15;   // + mf*16; row stride 32 shorts
  const int brow0 = wn * 64 + l15;   // + nf*16

  f32x4 acc[4][4];
  #pragma unroll
  for (int m = 0; m < 4; ++m)
    #pragma unroll
    for (int nn = 0; nn < 4; ++nn)
      acc[m][nn] = (f32x4){0.f, 0.f, 0.f, 0.f};

  const int NT = K >> 5;

  STG(0, 0);
  for (int t = 0; t < NT; ++t) {
    const int sl = (t & 1) * 12288, ns = sl ^ 12288;
    if (t + 1 < NT) {
      STG(ns, t + 1);
      WAITV(3);           // drains exactly tile t's 3 loads, tile t+1 stays in flight
    } else {
      WAITV(0);
    }
    __builtin_amdgcn_s_barrier();

    const unsigned short* lb = lds + sl;
    bf16x8 af[4], bfv[4];
    #pragma unroll
    for (int mf = 0; mf < 4; ++mf)
      af[mf] = *(const bf16x8*)&lb[(arow0 + mf * 16) * 32 + chA];
    #pragma unroll
    for (int nf = 0; nf < 4; ++nf)
      bfv[nf] = *(const bf16x8*)&lb[8192 + (brow0 + nf * 16) * 32 + chA];
    __builtin_amdgcn_s_setprio(1);
    #pragma unroll
    for (int mf = 0; mf < 4; ++mf)
      #pragma unroll
      for (int nf = 0; nf < 4; ++nf)
        acc[mf][nf] = __builtin_amdgcn_mfma_f32_16x16x32_bf16(af[mf], bfv[nf], acc[mf][nf], 0, 0, 0);
    __builtin_amdgcn_s_setprio(0);
    __builtin_amdgcn_s_barrier();   // all waves done reading slot sl before t+1 restages it
  }
#undef STG

  // epilogue
  const int batch = bm >> 2;         // 256-row blocks never straddle a batch
  const size_t row0 = (size_t)bm * 256 + wm * 64;
  const int col0 = bn * 128 + wn * 64;
  #pragma unroll
  for (int nf = 0; nf < 4; ++nf) {
    const int colg = col0 + nf * 16 + l15;
    const float bv = bias[colg];
    float g2 = 0.0f;
    if constexpr (EPI == 1 || EPI == 3) g2 = ada[(size_t)batch * ADAN + ada_off + colg];
    #pragma unroll
    for (int mf = 0; mf < 4; ++mf) {
      #pragma unroll
      for (int r = 0; r < 4; ++r) {
        const size_t idx = (row0 + mf * 16 + lg * 4 + r) * (size_t)N + colg;
        const float v = acc[mf][nf][r] + bv;
        if constexpr (EPI == 0)      out_bf[idx] = f32_to_bf16(v);
        else if constexpr (EPI == 2) out_bf[idx] = f32_to_bf16(gelu_exact(v));
        else if constexpr (EPI == 1) out_f[idx] = resid[idx] + g2 * v;
        else                         out_f[idx] = out_f[idx] + g2 * v;
      }
    }
  }
}

// ---------------- per-token head attention ----------------
__global__ __launch_bounds__(256) void attn_kernel(const unsigned short* __restrict__ qkv,
                                                   unsigned short* __restrict__ y) {
  const int tid = threadIdx.x, w = tid >> 6, lane = tid & 63;
  const int l15 = lane & 15, lg = lane >> 4;
  const int tok = blockIdx.x * 4 + w;
  const int n = tok >> 10, t = tok & 1023;

  __shared__ unsigned short Pl[4][16 * 32];
  __shared__ unsigned short Vl[4][16 * 80];

  for (int i = lane; i < 16 * 32; i += 64)
    if ((i & 31) >= 16) Pl[w][i] = 0;

  const size_t rowb = (size_t)tok * QKVN;
  const float scale = 0.11785113019775793f;  // 72^-0.5

  bf16x8 aq[3];
  #pragma unroll
  for (int kk = 0; kk < 3; ++kk) {
    const int d0 = kk * 32 + lg * 8;
    aq[kk] = (d0 < DHH) ? *(const bf16x8*)&qkv[rowb + l15 * DHH + d0] : zero_bf16x8();
  }

  for (int c = lane; c < 144; c += 64) {
    const int r = c / 9, cc = (c % 9) * 8;
    *(short8*)&Vl[w][r * 80 + cc] = *(const short8*)&qkv[rowb + 2 * DD + r * DHH + cc];
  }

  f32x4 s = (f32x4){0.f, 0.f, 0.f, 0.f};
  #pragma unroll
  for (int kk = 0; kk < 3; ++kk) {
    const int d0 = kk * 32 + lg * 8;
    bf16x8 bk = (d0 < DHH) ? *(const bf16x8*)&qkv[rowb + DD + l15 * DHH + d0] : zero_bf16x8();
    s = __builtin_amdgcn_mfma_f32_16x16x32_bf16(aq[kk], bk, s, 0, 0, 0);
  }

  float p[4], mx[4], ssum[4];
  #pragma unroll
  for (int r = 0; r < 4; ++r) { p[r] = s[r] * scale; mx[r] = p[r]; }
  #pragma unroll
  for (int mk = 1; mk <= 8; mk <<= 1)
    #pragma unroll
    for (int r = 0; r < 4; ++r) mx[r] = fmaxf(mx[r], __shfl_xor(mx[r], mk));
  #pragma unroll
  for (int r = 0; r < 4; ++r) { p[r] = __expf(p[r] - mx[r]); ssum[r] = p[r]; }
  #pragma unroll
  for (int mk = 1; mk <= 8; mk <<= 1)
    #pragma unroll
    for (int r = 0; r < 4; ++r) ssum[r] += __shfl_xor(ssum[r], mk);

  #pragma unroll
  for (int r = 0; r < 4; ++r)
    Pl[w][(lg * 4 + r) * 32 + l15] = f32_to_bf16(p[r] / ssum[r]);

  bf16x8 pa = *(const bf16x8*)&Pl[w][l15 * 32 + lg * 8];
  const int kb = (lg & 1) * 8;
  f32x4 o[5];
  #pragma unroll
  for (int df = 0; df < 5; ++df) {
    short8 bvv;
    #pragma unroll
    for (int j = 0; j < 8; ++j)
      bvv[j] = (short)Vl[w][(kb + j) * 80 + df * 16 + l15];
    o[df] = __builtin_amdgcn_mfma_f32_16x16x32_bf16(
        pa, __builtin_bit_cast(bf16x8, bvv), (f32x4){0.f, 0.f, 0.f, 0.f}, 0, 0, 0);
  }

  unsigned short* yb = y + (size_t)n * (TD * DD);
  #pragma unroll
  for (int df = 0; df < 5; ++df) {
    const int d = df * 16 + l15;
    if (d < DHH) {
      #pragma unroll
      for (int r = 0; r < 4; ++r) {
        const int h = lg * 4 + r;
        yb[h * 73728 + t * DHH + d] = f32_to_bf16(o[df][r]);
      }
    }
  }
}

// ---------------- host launch ----------------
extern "C" void kernel_launch(void* const* d_in, const int* in_sizes, int n_in,
                              void* d_out, int out_size, void* d_ws, size_t ws_size,
                              hipStream_t stream) {
  (void)in_sizes; (void)n_in; (void)out_size; (void)ws_size;
  const float* x      = (const float*)d_in[0];
  const float* c      = (const float*)d_in[1];
  const float* qkv_w  = (const float*)d_in[2];
  const float* qkv_b  = (const float*)d_in[3];
  const float* proj_w = (const float*)d_in[4];
  const float* proj_b = (const float*)d_in[5];
  const float* fc1_w  = (const float*)d_in[6];
  const float* fc1_b  = (const float*)d_in[7];
  const float* fc2_w  = (const float*)d_in[8];
  const float* fc2_b  = (const float*)d_in[9];
  const float* ada_w  = (const float*)d_in[10];
  const float* ada_b  = (const float*)d_in[11];
  float* out = (float*)d_out;

  char* ws = (char*)d_ws;
  unsigned short* hbuf    = (unsigned short*)ws;               // 302MB region (qkv | attn-y | h)
  unsigned short* qkvbuf  = hbuf;
  unsigned short* attnbuf = hbuf + (size_t)MROWS * QKVN;
  size_t off = 301989888ull;
  unsigned short* xm    = (unsigned short*)(ws + off); off += 75497472ull;
  unsigned short* wtq   = (unsigned short*)(ws + off); off += (size_t)QKVN * DD * 2;
  unsigned short* wtp   = (unsigned short*)(ws + off); off += (size_t)DD * DD * 2;
  unsigned short* wtf1  = (unsigned short*)(ws + off); off += (size_t)MLPD * DD * 2;
  unsigned short* wtf2  = (unsigned short*)(ws + off); off += (size_t)DD * MLPD * 2;
  float*          adab  = (float*)(ws + off); off += 884736ull;

  const dim3 tb(32, 8);
  hipLaunchKernelGGL(wtrans_kernel, dim3(QKVN / 32, DD / 32), tb, 0, stream, qkv_w, wtq, DD, QKVN);
  hipLaunchKernelGGL(wtrans_kernel, dim3(DD / 32, DD / 32),   tb, 0, stream, proj_w, wtp, DD, DD);
  hipLaunchKernelGGL(wtrans_kernel, dim3(MLPD / 32, DD / 32), tb, 0, stream, fc1_w, wtf1, DD, MLPD);
  hipLaunchKernelGGL(wtrans_kernel, dim3(DD / 32, MLPD / 32), tb, 0, stream, fc2_w, wtf2, MLPD, DD);

  hipLaunchKernelGGL(ada_kernel, dim3(ADAN / 256, 32), dim3(256), 0, stream, c, ada_w, ada_b, adab);

  hipLaunchKernelGGL(ln_mod_kernel, dim3(MROWS), dim3(256), 0, stream, x, adab, 0, xm);

  // qkv: 128 bm x 27 bn
  hipLaunchKernelGGL((gemm3b<0>), dim3(128 * 27), dim3(512), 0, stream,
                     xm, wtq, qkv_b, nullptr, 0, nullptr, qkvbuf, nullptr, QKVN, DD, 27);

  hipLaunchKernelGGL(attn_kernel, dim3(MROWS / 4), dim3(256), 0, stream, qkvbuf, attnbuf);

  // proj: 128 x 9
  hipLaunchKernelGGL((gemm3b<1>), dim3(128 * 9), dim3(512), 0, stream,
                     attnbuf, wtp, proj_b, adab, 2304, x, nullptr, out, DD, DD, 9);

  hipLaunchKernelGGL(ln_mod_kernel, dim3(MROWS), dim3(256), 0, stream, out, adab, 3456, xm);

  // fc1: 128 x 36
  hipLaunchKernelGGL((gemm3b<2>), dim3(128 * 36), dim3(512), 0, stream,
                     xm, wtf1, fc1_b, nullptr, 0, nullptr, hbuf, nullptr, MLPD, DD, 36);

  // fc2: 128 x 9, K=4608
  hipLaunchKernelGGL((gemm3b<3>), dim3(128 * 9), dim3(512), 0, stream,
                     hbuf, wtf2, fc2_b, adab, 5760, nullptr, nullptr, out, DD, MLPD, 9);
}